// Round 2
// baseline (84.787 us; speedup 1.0000x reference)
//
#include <hip/hip_runtime.h>
#include <math.h>

#define NV 5000   // nodes
#define BATCH 16
#define DD 12     // input feature dim
#define HH 64     // hidden dim
#define KK 30     // virtual nodes

// ---------------- Kernel A: s[m] = adj[m,m] / deg[m] ----------------
// deg[m] = sum_j adj[m,j] + sum_k adjk1[k,m]
__global__ __launch_bounds__(256) void s_kernel(const float* __restrict__ adj,
                                                const float* __restrict__ adjk1,
                                                float* __restrict__ s) {
    const int m = blockIdx.x;
    const float4* row = reinterpret_cast<const float4*>(adj + (size_t)m * NV);
    float acc = 0.f;
    for (int i = threadIdx.x; i < NV / 4; i += 256) {
        float4 v = row[i];
        acc += (v.x + v.y) + (v.z + v.w);
    }
    // wave reduce (64 lanes)
    for (int off = 32; off > 0; off >>= 1) acc += __shfl_down(acc, off, 64);
    __shared__ float part[4];
    if ((threadIdx.x & 63) == 0) part[threadIdx.x >> 6] = acc;
    __syncthreads();
    if (threadIdx.x == 0) {
        float deg = (part[0] + part[1]) + (part[2] + part[3]);
        float cs = 0.f;
        #pragma unroll
        for (int k = 0; k < KK; ++k) cs += adjk1[(size_t)k * NV + m];
        deg += cs;
        s[m] = adj[(size_t)m * NV + m] / deg;
    }
}

// ---------------- Kernel B: per-node 3-layer gated GCN chain ----------------
// NOTE on precision: outputs scale like s^3 ~ 1e-11; tanh MUST be accurate for
// tiny arguments (tanh(x)=x-x^3/3...). An expf-based tanh rounds exp(2x) to 1.0f
// for |x|<6e-8 and returns 0 => 100% relative error (this was the round-0/1
// failure). libm tanhf has the correct small-arg path. The sigmoid gate only
// multiplies a tiny value, so __expf precision there is irrelevant.
__device__ __forceinline__ float fsig(float x) {
    return 1.0f / (1.0f + __expf(-x));
}
__device__ __forceinline__ float ftanh(float x) {
    return tanhf(x);
}

#define WAVES 8
#define NPW 4                 // nodes per wave
#define NPB (WAVES * NPW)     // 32 nodes per block

__global__ __launch_bounds__(512) void gcn_kernel(
    const float* __restrict__ x, const float* __restrict__ s,
    const float* __restrict__ W1, const float* __restrict__ b1,
    const float* __restrict__ W11, const float* __restrict__ b11,
    const float* __restrict__ W2, const float* __restrict__ b2,
    const float* __restrict__ W22, const float* __restrict__ b22,
    const float* __restrict__ W3, const float* __restrict__ b3,
    const float* __restrict__ W33, const float* __restrict__ b33,
    float* __restrict__ out) {
    __shared__ float W1s[DD * HH], W11s[DD * HH];
    __shared__ float W2s[HH * HH], W22s[HH * HH], W3s[HH * HH], W33s[HH * HH];
    __shared__ float ost[WAVES][HH * NPW];

    const int tid = threadIdx.x;
    // cooperative weight staging (float4 vectorized)
    {
        float4* d1 = (float4*)W1s;  const float4* s1 = (const float4*)W1;
        float4* d11 = (float4*)W11s; const float4* s11 = (const float4*)W11;
        #pragma unroll
        for (int i = tid; i < (DD * HH) / 4; i += 512) { d1[i] = s1[i]; d11[i] = s11[i]; }
        float4* d2 = (float4*)W2s;   const float4* s2 = (const float4*)W2;
        float4* d22 = (float4*)W22s; const float4* s22 = (const float4*)W22;
        float4* d3 = (float4*)W3s;   const float4* s3 = (const float4*)W3;
        float4* d33 = (float4*)W33s; const float4* s33 = (const float4*)W33;
        for (int i = tid; i < (HH * HH) / 4; i += 512) {
            d2[i] = s2[i]; d22[i] = s22[i]; d3[i] = s3[i]; d33[i] = s33[i];
        }
    }
    __syncthreads();

    const int lane = tid & 63;
    const int wid = tid >> 6;
    float* myo = ost[wid];

    const int g0 = blockIdx.x * NPB + wid * NPW;  // global node id base (b*NV+m)

    // per-node scalars: s value + input features (12 floats each, 16B aligned)
    float sv[NPW];
    float xr[NPW][DD];
    #pragma unroll
    for (int i = 0; i < NPW; ++i) {
        const int g = g0 + i;
        const int m = g % NV;
        sv[i] = s[m];
        const float4* xp = reinterpret_cast<const float4*>(x + (size_t)g * DD);
        float4 v0 = xp[0], v1 = xp[1], v2 = xp[2];
        xr[i][0] = v0.x; xr[i][1] = v0.y; xr[i][2] = v0.z; xr[i][3] = v0.w;
        xr[i][4] = v1.x; xr[i][5] = v1.y; xr[i][6] = v1.z; xr[i][7] = v1.w;
        xr[i][8] = v2.x; xr[i][9] = v2.y; xr[i][10] = v2.z; xr[i][11] = v2.w;
    }

    float a[NPW], c[NPW];

    // ---- Layer 1: D=12 -> H=64 ----
    {
        const float bv = b1[lane], bvv = b11[lane];
        #pragma unroll
        for (int i = 0; i < NPW; ++i) { a[i] = 0.f; c[i] = 0.f; }
        #pragma unroll
        for (int d = 0; d < DD; ++d) {
            float w = W1s[d * HH + lane], ww = W11s[d * HH + lane];
            #pragma unroll
            for (int i = 0; i < NPW; ++i) {
                a[i] = fmaf(xr[i][d], w, a[i]);
                c[i] = fmaf(xr[i][d], ww, c[i]);
            }
        }
        float t0 = ftanh(fmaf(sv[0], a[0], bv)) * fsig(fmaf(sv[0], c[0], bvv));
        float t1 = ftanh(fmaf(sv[1], a[1], bv)) * fsig(fmaf(sv[1], c[1], bvv));
        float t2 = ftanh(fmaf(sv[2], a[2], bv)) * fsig(fmaf(sv[2], c[2], bvv));
        float t3 = ftanh(fmaf(sv[3], a[3], bv)) * fsig(fmaf(sv[3], c[3], bvv));
        *reinterpret_cast<float4*>(&myo[lane * NPW]) = make_float4(t0, t1, t2, t3);
    }
    __syncthreads();

    // ---- Layers 2 and 3: H=64 -> H=64 (gated) ----
    #define HLAYER(Ws, WWs, bp, bbp, STORE_OUT)                                   \
    {                                                                             \
        const float bv = bp[lane], bvv = bbp[lane];                               \
        _Pragma("unroll")                                                         \
        for (int i = 0; i < NPW; ++i) { a[i] = 0.f; c[i] = 0.f; }                 \
        _Pragma("unroll 16")                                                      \
        for (int j = 0; j < HH; ++j) {                                            \
            float4 o4 = *reinterpret_cast<const float4*>(&myo[j * NPW]);          \
            float w = Ws[j * HH + lane], ww = WWs[j * HH + lane];                 \
            a[0] = fmaf(o4.x, w, a[0]); c[0] = fmaf(o4.x, ww, c[0]);              \
            a[1] = fmaf(o4.y, w, a[1]); c[1] = fmaf(o4.y, ww, c[1]);              \
            a[2] = fmaf(o4.z, w, a[2]); c[2] = fmaf(o4.z, ww, c[2]);              \
            a[3] = fmaf(o4.w, w, a[3]); c[3] = fmaf(o4.w, ww, c[3]);              \
        }                                                                         \
        float t0 = ftanh(fmaf(sv[0], a[0], bv)) * fsig(fmaf(sv[0], c[0], bvv));  \
        float t1 = ftanh(fmaf(sv[1], a[1], bv)) * fsig(fmaf(sv[1], c[1], bvv));  \
        float t2 = ftanh(fmaf(sv[2], a[2], bv)) * fsig(fmaf(sv[2], c[2], bvv));  \
        float t3 = ftanh(fmaf(sv[3], a[3], bv)) * fsig(fmaf(sv[3], c[3], bvv));  \
        if (STORE_OUT) {                                                          \
            out[(size_t)(g0 + 0) * HH + lane] = t0;                               \
            out[(size_t)(g0 + 1) * HH + lane] = t1;                               \
            out[(size_t)(g0 + 2) * HH + lane] = t2;                               \
            out[(size_t)(g0 + 3) * HH + lane] = t3;                               \
        } else {                                                                  \
            __syncthreads();                                                      \
            *reinterpret_cast<float4*>(&myo[lane * NPW]) =                        \
                make_float4(t0, t1, t2, t3);                                      \
            __syncthreads();                                                      \
        }                                                                         \
    }

    HLAYER(W2s, W22s, b2, b22, 0)
    HLAYER(W3s, W33s, b3, b33, 1)
    #undef HLAYER
}

extern "C" void kernel_launch(void* const* d_in, const int* in_sizes, int n_in,
                              void* d_out, int out_size, void* d_ws, size_t ws_size,
                              hipStream_t stream) {
    const float* x     = (const float*)d_in[0];
    const float* adj   = (const float*)d_in[1];
    const float* adjk1 = (const float*)d_in[2];
    const float* W1  = (const float*)d_in[3];  const float* b1  = (const float*)d_in[4];
    const float* W11 = (const float*)d_in[5];  const float* b11 = (const float*)d_in[6];
    const float* W2  = (const float*)d_in[7];  const float* b2  = (const float*)d_in[8];
    const float* W22 = (const float*)d_in[9];  const float* b22 = (const float*)d_in[10];
    const float* W3  = (const float*)d_in[11]; const float* b3  = (const float*)d_in[12];
    const float* W33 = (const float*)d_in[13]; const float* b33 = (const float*)d_in[14];
    float* out = (float*)d_out;
    float* s = (float*)d_ws;  // 5000 floats = 20 KB scratch

    s_kernel<<<NV, 256, 0, stream>>>(adj, adjk1, s);

    const int total_nodes = BATCH * NV;            // 80000
    const int blocks = total_nodes / NPB;          // 2500
    gcn_kernel<<<blocks, 512, 0, stream>>>(x, s, W1, b1, W11, b11,
                                           W2, b2, W22, b22, W3, b3, W33, b33, out);
}

// Round 3
// 69.806 us; speedup vs baseline: 1.2146x; 1.2146x over previous
//
#include <hip/hip_runtime.h>
#include <math.h>

#define NV 5000   // nodes
#define BATCH 16
#define DD 12     // input feature dim
#define HH 64     // hidden dim
#define KK 30     // virtual nodes

// ---------------- Kernel A: s[m] = adj[m,m] / deg[m] ----------------
__global__ __launch_bounds__(256) void s_kernel(const float* __restrict__ adj,
                                                const float* __restrict__ adjk1,
                                                float* __restrict__ s) {
    const int m = blockIdx.x;
    const float4* row = reinterpret_cast<const float4*>(adj + (size_t)m * NV);
    float acc = 0.f;
    for (int i = threadIdx.x; i < NV / 4; i += 256) {
        float4 v = row[i];
        acc += (v.x + v.y) + (v.z + v.w);
    }
    for (int off = 32; off > 0; off >>= 1) acc += __shfl_down(acc, off, 64);
    __shared__ float part[4];
    if ((threadIdx.x & 63) == 0) part[threadIdx.x >> 6] = acc;
    __syncthreads();
    if (threadIdx.x == 0) {
        float deg = (part[0] + part[1]) + (part[2] + part[3]);
        float cs = 0.f;
        #pragma unroll
        for (int k = 0; k < KK; ++k) cs += adjk1[(size_t)k * NV + m];
        deg += cs;
        s[m] = adj[(size_t)m * NV + m] / deg;
    }
}

// ---------------- activation: tanh(A) * sigmoid(C) ----------------
// Args are ~1e-3 in magnitude (bounded by s ~ 4e-4). Taylor polys are exact to
// fp32 rounding for |x|<=0.04 (rel err <= 2e-10). Cold exec-masked fallback to
// accurate routines for larger args (never taken with this data, but correct).
// libm tanhf is required in the fallback: expf-based tanh returns 0 for tiny
// args (the round-0 failure).
__device__ __forceinline__ float act(float A, float C) {
    float a2 = A * A;
    float th = A * fmaf(a2, fmaf(a2, 0.13333334f, -0.33333334f), 1.0f);
    float c2 = C * C;
    float sg = fmaf(C, fmaf(c2, -0.020833334f, 0.25f), 0.5f);
    if (__builtin_expect(fabsf(A) > 0.04f, 0)) th = tanhf(A);
    if (__builtin_expect(fabsf(C) > 0.04f, 0)) sg = 1.0f / (1.0f + __expf(-C));
    return th * sg;
}

#define WAVES 8
#define NPW 8                 // nodes per wave
#define NPB (WAVES * NPW)     // 64 nodes per block
#define NBLK ((BATCH * NV) / NPB)  // 1250 blocks

// LDS: WI2/WI3 interleaved [j][0..63]=W, [j][64..127]=WW -> 32 KiB each;
// ost wave-private o-staging 16 KiB. Total 80 KiB -> 2 blocks/CU.
__global__ __launch_bounds__(512) void gcn_kernel(
    const float* __restrict__ x, const float* __restrict__ s,
    const float* __restrict__ W1, const float* __restrict__ b1,
    const float* __restrict__ W11, const float* __restrict__ b11,
    const float* __restrict__ W2, const float* __restrict__ b2,
    const float* __restrict__ W22, const float* __restrict__ b22,
    const float* __restrict__ W3, const float* __restrict__ b3,
    const float* __restrict__ W33, const float* __restrict__ b33,
    float* __restrict__ out) {
    __shared__ float WI2[HH * 128];
    __shared__ float WI3[HH * 128];
    __shared__ float ost[WAVES][HH * NPW];

    const int tid = threadIdx.x;
    // cooperative interleaved staging of layer-2/3 weights (float4)
    {
        const float4* W2v = (const float4*)W2;  const float4* W22v = (const float4*)W22;
        const float4* W3v = (const float4*)W3;  const float4* W33v = (const float4*)W33;
        float4* d2 = (float4*)WI2;  float4* d3 = (float4*)WI3;
        #pragma unroll
        for (int q = tid; q < 2048; q += 512) {
            const int j = q >> 5, c4 = q & 31;
            const float4* s2 = (c4 < 16) ? (W2v + j * 16 + c4) : (W22v + j * 16 + (c4 - 16));
            const float4* s3 = (c4 < 16) ? (W3v + j * 16 + c4) : (W33v + j * 16 + (c4 - 16));
            d2[q] = *s2;
            d3[q] = *s3;
        }
    }

    const int lane = tid & 63;
    const int wid = __builtin_amdgcn_readfirstlane(tid >> 6);
    float* myo = ost[wid];
    const int g0 = blockIdx.x * NPB + wid * NPW;  // wave-uniform node base (b*NV+m)

    // ---- Layer 1: D=12 -> H=64, x read via wave-uniform (scalar) loads ----
    float w1r[DD], w11r[DD];
    #pragma unroll
    for (int d = 0; d < DD; ++d) { w1r[d] = W1[d * HH + lane]; w11r[d] = W11[d * HH + lane]; }
    const float bv1 = b1[lane], bvv1 = b11[lane];

    float sv[NPW];
    float a[NPW], c[NPW];
    #pragma unroll
    for (int i = 0; i < NPW; ++i) {
        const int g = g0 + i;
        sv[i] = s[g % NV];
        const float* xp = x + (size_t)g * DD;
        float ai = 0.f, ci = 0.f;
        #pragma unroll
        for (int d = 0; d < DD; ++d) {
            const float xv = xp[d];
            ai = fmaf(xv, w1r[d], ai);
            ci = fmaf(xv, w11r[d], ci);
        }
        a[i] = ai; c[i] = ci;
    }
    {
        float t[NPW];
        #pragma unroll
        for (int i = 0; i < NPW; ++i)
            t[i] = act(fmaf(sv[i], a[i], bv1), fmaf(sv[i], c[i], bvv1));
        *reinterpret_cast<float4*>(&myo[lane * NPW])     = make_float4(t[0], t[1], t[2], t[3]);
        *reinterpret_cast<float4*>(&myo[lane * NPW + 4]) = make_float4(t[4], t[5], t[6], t[7]);
    }

    __syncthreads();  // WI2/WI3 staged (only block-wide barrier needed; ost is wave-private)

    // ---- Layers 2 and 3: H=64 -> H=64 (gated) ----
    #define HLAYER(WI, bp, bbp, STORE_OUT)                                        \
    {                                                                             \
        const float bv = bp[lane], bvv = bbp[lane];                               \
        _Pragma("unroll")                                                         \
        for (int i = 0; i < NPW; ++i) { a[i] = 0.f; c[i] = 0.f; }                 \
        _Pragma("unroll 8")                                                       \
        for (int j = 0; j < HH; ++j) {                                            \
            float4 o0 = *reinterpret_cast<const float4*>(&myo[j * NPW]);          \
            float4 o1 = *reinterpret_cast<const float4*>(&myo[j * NPW + 4]);      \
            float w  = WI[j * 128 + lane];                                        \
            float ww = WI[j * 128 + 64 + lane];                                   \
            a[0] = fmaf(o0.x, w, a[0]); c[0] = fmaf(o0.x, ww, c[0]);              \
            a[1] = fmaf(o0.y, w, a[1]); c[1] = fmaf(o0.y, ww, c[1]);              \
            a[2] = fmaf(o0.z, w, a[2]); c[2] = fmaf(o0.z, ww, c[2]);              \
            a[3] = fmaf(o0.w, w, a[3]); c[3] = fmaf(o0.w, ww, c[3]);              \
            a[4] = fmaf(o1.x, w, a[4]); c[4] = fmaf(o1.x, ww, c[4]);              \
            a[5] = fmaf(o1.y, w, a[5]); c[5] = fmaf(o1.y, ww, c[5]);              \
            a[6] = fmaf(o1.z, w, a[6]); c[6] = fmaf(o1.z, ww, c[6]);              \
            a[7] = fmaf(o1.w, w, a[7]); c[7] = fmaf(o1.w, ww, c[7]);              \
        }                                                                         \
        float t[NPW];                                                             \
        _Pragma("unroll")                                                         \
        for (int i = 0; i < NPW; ++i)                                             \
            t[i] = act(fmaf(sv[i], a[i], bv), fmaf(sv[i], c[i], bvv));            \
        if (STORE_OUT) {                                                          \
            _Pragma("unroll")                                                     \
            for (int i = 0; i < NPW; ++i)                                         \
                out[(size_t)(g0 + i) * HH + lane] = t[i];                         \
        } else {                                                                  \
            *reinterpret_cast<float4*>(&myo[lane * NPW]) =                        \
                make_float4(t[0], t[1], t[2], t[3]);                              \
            *reinterpret_cast<float4*>(&myo[lane * NPW + 4]) =                    \
                make_float4(t[4], t[5], t[6], t[7]);                              \
        }                                                                         \
    }

    HLAYER(WI2, b2, b22, 0)
    HLAYER(WI3, b3, b33, 1)
    #undef HLAYER
}

extern "C" void kernel_launch(void* const* d_in, const int* in_sizes, int n_in,
                              void* d_out, int out_size, void* d_ws, size_t ws_size,
                              hipStream_t stream) {
    const float* x     = (const float*)d_in[0];
    const float* adj   = (const float*)d_in[1];
    const float* adjk1 = (const float*)d_in[2];
    const float* W1  = (const float*)d_in[3];  const float* b1  = (const float*)d_in[4];
    const float* W11 = (const float*)d_in[5];  const float* b11 = (const float*)d_in[6];
    const float* W2  = (const float*)d_in[7];  const float* b2  = (const float*)d_in[8];
    const float* W22 = (const float*)d_in[9];  const float* b22 = (const float*)d_in[10];
    const float* W3  = (const float*)d_in[11]; const float* b3  = (const float*)d_in[12];
    const float* W33 = (const float*)d_in[13]; const float* b33 = (const float*)d_in[14];
    float* out = (float*)d_out;
    float* s = (float*)d_ws;  // 5000 floats scratch

    s_kernel<<<NV, 256, 0, stream>>>(adj, adjk1, s);
    gcn_kernel<<<NBLK, 512, 0, stream>>>(x, s, W1, b1, W11, b11,
                                         W2, b2, W22, b22, W3, b3, W33, b33, out);
}